// Round 6
// baseline (118.728 us; speedup 1.0000x reference)
//
#include <hip/hip_runtime.h>
#include <cstdint>

// VQ-VAE vector quantizer, MI355X (gfx950). Round 6.
// Evidence r3-r5: kernel time (66/45/43us) is invariant to ds-floor (10/20/10us)
// and waves/SIMD (1/2/4) -> neither pipe is the limiter; the constant is the
// per-slice prefetch->barrier(vmcnt0 drain)->compute pipeline. Remove it:
//  - vq_score: block (rowTile,g) holds 512 codes fp8 RESIDENT in LDS (64 KB,
//    staged once, ONE barrier), scores 128 rows; 2 row-strips/wave -> 1
//    ds_read_b128 : 4 MFMAs -> MFMA-bound (19.9k cyc/CU vs ds 12.3k), 8
//    indep acc chains/wave, zero mid-loop barriers/outstanding vmem.
//    Writes per-row (best,idx) float2 to ws; g==0 also writes sum(z^2).
//  - vq_final: merge the two code-group pairs per row, gather emb[idx],
//    write out, loss = sum(zsq + best/1024) * 1.25/N. Write-bound ~6us.
//  - fp8 e4m3 scoring math identical to r5 (verified absmax 1.95e-3).

typedef float f32x4 __attribute__((ext_vector_type(4)));
typedef long  l2    __attribute__((ext_vector_type(2)));
typedef _Float16 f16;
typedef f16 f16x8 __attribute__((ext_vector_type(8)));

#define D_DIM 256
#define K_CODES 1024
#define NROWS_TOT 32768
#define SLICE_BYTES 16384        // 64 codes fp8
#define GROUP_BYTES 65536        // 512 codes = 8 slices

__device__ __forceinline__ void async_copy16(const void* g, void* l) {
    __builtin_amdgcn_global_load_lds(
        (const __attribute__((address_space(1))) void*)g,
        (__attribute__((address_space(3))) void*)l, 16, 0, 0);
}

__device__ __forceinline__ long pack_fp8x8(float x0, float x1, float x2, float x3,
                                           float x4, float x5, float x6, float x7) {
    int w0 = __builtin_amdgcn_cvt_pk_fp8_f32(x0, x1, 0, false);
    w0     = __builtin_amdgcn_cvt_pk_fp8_f32(x2, x3, w0, true);
    int w1 = __builtin_amdgcn_cvt_pk_fp8_f32(x4, x5, 0, false);
    w1     = __builtin_amdgcn_cvt_pk_fp8_f32(x6, x7, w1, true);
    int2 p = {w0, w1};
    return __builtin_bit_cast(long, p);
}

// ---- Prep (verified r5): zero loss slot; emb -> fp8 (x1024) in
// fragment-slice-linear order (16 slices of 64 codes; within slice chunk
// rem = ct*256 + t*64 + q*16 + m holds k-dims [t*64+q*8,+8) and
// [t*64+32+q*8,+8) of code sp*64+ct*16+m); eTe = 1024*||e||^2. grid 256x256.
__global__ __launch_bounds__(256) void vq_prep(const float* __restrict__ emb,
                                               char* __restrict__ emb8,
                                               float* __restrict__ eTe,
                                               float* __restrict__ loss_slot) {
    const int tid = threadIdx.x, wave = tid >> 6, lane = tid & 63;
    if (blockIdx.x == 0 && tid == 0) *loss_slot = 0.0f;

    if (blockIdx.x < 64) {
        int ch  = blockIdx.x * 256 + tid;     // 16384 chunks
        int sp  = ch >> 10;
        int rem = ch & 1023;
        int ct  = rem >> 8;
        int t   = (rem >> 6) & 3;
        int l   = rem & 63;
        int qq  = l >> 4, mm = l & 15;
        int code = sp * 64 + ct * 16 + mm;
        const float* p = emb + (size_t)code * D_DIM;
        int b0 = t * 64 + qq * 8;
        int b1 = b0 + 32;
        float4 v0 = *(const float4*)(p + b0);
        float4 v1 = *(const float4*)(p + b0 + 4);
        float4 v2 = *(const float4*)(p + b1);
        float4 v3 = *(const float4*)(p + b1 + 4);
        l2 o;
        o.x = pack_fp8x8(v0.x * 1024.f, v0.y * 1024.f, v0.z * 1024.f, v0.w * 1024.f,
                         v1.x * 1024.f, v1.y * 1024.f, v1.z * 1024.f, v1.w * 1024.f);
        o.y = pack_fp8x8(v2.x * 1024.f, v2.y * 1024.f, v2.z * 1024.f, v2.w * 1024.f,
                         v3.x * 1024.f, v3.y * 1024.f, v3.z * 1024.f, v3.w * 1024.f);
        *(l2*)(emb8 + (size_t)ch * 16) = o;
    }

    int code = blockIdx.x * 4 + wave;
    float4 v = ((const float4*)(emb + (size_t)code * D_DIM))[lane];
    float s = v.x * v.x + v.y * v.y + v.z * v.z + v.w * v.w;
    #pragma unroll
    for (int off = 32; off >= 1; off >>= 1) s += __shfl_down(s, off);
    if (lane == 0) eTe[code] = 1024.0f * s;
}

// ---- Score: grid 512 = 256 rowTiles x 2 code-groups. 256 thr (4 waves),
// 32 rows/wave (2 strips of 16). Codebook group resident in LDS.
__global__ __launch_bounds__(256, 2) void vq_score(const float* __restrict__ z,
                                                   const char* __restrict__ emb8,
                                                   const float* __restrict__ eTe,
                                                   float2* __restrict__ pairs,
                                                   float* __restrict__ zsq_g) {
    __shared__ __align__(16) char sB[GROUP_BYTES];   // 64 KB -> 2 blocks/CU

    const int tid  = threadIdx.x;
    const int wave = tid >> 6;        // 0..3
    const int lane = tid & 63;
    const int m    = lane & 15;       // A row / B col (code) / C col
    const int q    = lane >> 4;       // k-group / C row-group
    const int g    = blockIdx.x & 1;  // code group (adjacent blocks share z rows)
    const int rowTile = blockIdx.x >> 1;
    const size_t rowbase = (size_t)rowTile * 128 + wave * 32;

    // Stage the whole 64 KB group codebook once (async, lane-linear 16 B).
    {
        const char* src = emb8 + (size_t)g * GROUP_BYTES;
        #pragma unroll
        for (int ii = 0; ii < 16; ii++) {
            int ch = ii * 256 + tid;
            async_copy16(src + (size_t)ch * 16, sB + (size_t)ch * 16);
        }
    }

    // A fragments: 2 strips x 16 rows -> fp8 regs (32 VGPRs) + sum(z^2).
    long A8[2][8];
    float zs[2] = {0.f, 0.f};
    #pragma unroll
    for (int st = 0; st < 2; st++) {
        const float* zr = z + (rowbase + st * 16 + m) * D_DIM;
        #pragma unroll
        for (int s = 0; s < 8; s++) {
            const float* p = zr + s * 32 + q * 8;
            float4 v0 = *(const float4*)p;
            float4 v1 = *(const float4*)(p + 4);
            zs[st] += v0.x * v0.x + v0.y * v0.y + v0.z * v0.z + v0.w * v0.w
                    + v1.x * v1.x + v1.y * v1.y + v1.z * v1.z + v1.w * v1.w;
            A8[st][s] = pack_fp8x8(v0.x, v0.y, v0.z, v0.w, v1.x, v1.y, v1.z, v1.w);
        }
    }
    if (g == 0) {   // one group writes per-row sum(z^2) for the loss
        #pragma unroll
        for (int st = 0; st < 2; st++) {
            float zr_ = zs[st] + __shfl_xor(zs[st], 16);
            zr_ += __shfl_xor(zr_, 32);
            if (q == 0) zsq_g[rowbase + st * 16 + m] = zr_;
        }
    }

    float best[2][4];
    int   bidx[2][4];
    #pragma unroll
    for (int st = 0; st < 2; st++)
        #pragma unroll
        for (int r = 0; r < 4; r++) { best[st][r] = __builtin_inff(); bidx[st][r] = 0; }

    __syncthreads();   // drains the async staging; sB read-only from here on

    #pragma unroll 1
    for (int sp = 0; sp < 8; sp++) {
        const char* B = sB + sp * SLICE_BYTES;
        const int cbase = g * 512 + sp * 64;
        float ete[4];
        #pragma unroll
        for (int ct = 0; ct < 4; ct++) ete[ct] = eTe[cbase + ct * 16 + m];

        f32x4 acc[4][2];
        #pragma unroll
        for (int ct = 0; ct < 4; ct++)
            #pragma unroll
            for (int st = 0; st < 2; st++) acc[ct][st] = (f32x4){0.f, 0.f, 0.f, 0.f};

        // 4 t-steps: 4 ds_read_b128 feed 16 MFMAs (4 ct x 2 k-halves x 2 strips).
        #pragma unroll
        for (int t = 0; t < 4; t++) {
            l2 c0 = *(const l2*)(B + (size_t)(0 * 256 + t * 64 + lane) * 16);
            l2 c1 = *(const l2*)(B + (size_t)(1 * 256 + t * 64 + lane) * 16);
            l2 c2 = *(const l2*)(B + (size_t)(2 * 256 + t * 64 + lane) * 16);
            l2 c3 = *(const l2*)(B + (size_t)(3 * 256 + t * 64 + lane) * 16);
            acc[0][0] = __builtin_amdgcn_mfma_f32_16x16x32_fp8_fp8(A8[0][2*t],   c0.x, acc[0][0], 0, 0, 0);
            acc[1][0] = __builtin_amdgcn_mfma_f32_16x16x32_fp8_fp8(A8[0][2*t],   c1.x, acc[1][0], 0, 0, 0);
            acc[2][0] = __builtin_amdgcn_mfma_f32_16x16x32_fp8_fp8(A8[0][2*t],   c2.x, acc[2][0], 0, 0, 0);
            acc[3][0] = __builtin_amdgcn_mfma_f32_16x16x32_fp8_fp8(A8[0][2*t],   c3.x, acc[3][0], 0, 0, 0);
            acc[0][1] = __builtin_amdgcn_mfma_f32_16x16x32_fp8_fp8(A8[1][2*t],   c0.x, acc[0][1], 0, 0, 0);
            acc[1][1] = __builtin_amdgcn_mfma_f32_16x16x32_fp8_fp8(A8[1][2*t],   c1.x, acc[1][1], 0, 0, 0);
            acc[2][1] = __builtin_amdgcn_mfma_f32_16x16x32_fp8_fp8(A8[1][2*t],   c2.x, acc[2][1], 0, 0, 0);
            acc[3][1] = __builtin_amdgcn_mfma_f32_16x16x32_fp8_fp8(A8[1][2*t],   c3.x, acc[3][1], 0, 0, 0);
            acc[0][0] = __builtin_amdgcn_mfma_f32_16x16x32_fp8_fp8(A8[0][2*t+1], c0.y, acc[0][0], 0, 0, 0);
            acc[1][0] = __builtin_amdgcn_mfma_f32_16x16x32_fp8_fp8(A8[0][2*t+1], c1.y, acc[1][0], 0, 0, 0);
            acc[2][0] = __builtin_amdgcn_mfma_f32_16x16x32_fp8_fp8(A8[0][2*t+1], c2.y, acc[2][0], 0, 0, 0);
            acc[3][0] = __builtin_amdgcn_mfma_f32_16x16x32_fp8_fp8(A8[0][2*t+1], c3.y, acc[3][0], 0, 0, 0);
            acc[0][1] = __builtin_amdgcn_mfma_f32_16x16x32_fp8_fp8(A8[1][2*t+1], c0.y, acc[0][1], 0, 0, 0);
            acc[1][1] = __builtin_amdgcn_mfma_f32_16x16x32_fp8_fp8(A8[1][2*t+1], c1.y, acc[1][1], 0, 0, 0);
            acc[2][1] = __builtin_amdgcn_mfma_f32_16x16x32_fp8_fp8(A8[1][2*t+1], c2.y, acc[2][1], 0, 0, 0);
            acc[3][1] = __builtin_amdgcn_mfma_f32_16x16x32_fp8_fp8(A8[1][2*t+1], c3.y, acc[3][1], 0, 0, 0);
        }

        #pragma unroll
        for (int ct = 0; ct < 4; ct++) {
            int code = cbase + ct * 16 + m;
            #pragma unroll
            for (int st = 0; st < 2; st++)
                #pragma unroll
                for (int r = 0; r < 4; r++) {
                    float sc = fmaf(-2.0f, acc[ct][st][r], ete[ct]);
                    if (sc < best[st][r]) { best[st][r] = sc; bidx[st][r] = code; }
                }
        }
    }

    // Cross-lane argmin over the 16 column-lanes (first-index tie-break);
    // winner lane writes the (best, idx) pair for its row to ws.
    #pragma unroll
    for (int st = 0; st < 2; st++)
        #pragma unroll
        for (int r = 0; r < 4; r++) {
            float b  = best[st][r];
            int   bi = bidx[st][r];
            #pragma unroll
            for (int off = 8; off >= 1; off >>= 1) {
                float ob = __shfl_xor(b, off);
                int   oi = __shfl_xor(bi, off);
                if (ob < b || (ob == b && oi < bi)) { b = ob; bi = oi; }
            }
            if (m == 0) {
                size_t row = rowbase + st * 16 + q * 4 + r;
                float2 pr;
                pr.x = b;
                pr.y = __builtin_bit_cast(float, bi);
                pairs[(size_t)g * NROWS_TOT + row] = pr;
            }
        }
}

// ---- Final: merge the two groups, gather emb[idx], write out, loss.
// grid 512 x 256 thr (64 rows/block).
__global__ __launch_bounds__(256) void vq_final(const float* __restrict__ emb,
                                                const float2* __restrict__ pairs,
                                                const float* __restrict__ zsq_g,
                                                float* __restrict__ out,
                                                float* __restrict__ loss_slot,
                                                float loss_scale) {
    __shared__ float s_red[4];
    const int tid  = threadIdx.x;
    const int wave = tid >> 6;
    const int lane = tid & 63;
    const int m    = lane & 15;
    const int q    = lane >> 4;
    const size_t row = (size_t)blockIdx.x * 64 + wave * 16 + m;

    float2 p0 = pairs[row];
    float2 p1 = pairs[NROWS_TOT + row];
    bool take1 = (p1.x < p0.x);           // group-0 idx < group-1: tie -> 0
    int   idx  = __builtin_bit_cast(int, take1 ? p1.y : p0.y);
    float bsc  = take1 ? p1.x : p0.x;

    const float* er = emb + (size_t)idx * D_DIM;
    float* orow = out + row * D_DIM;
    #pragma unroll
    for (int s = 0; s < 8; s++) {
        int dd = s * 32 + q * 8;
        *(float4*)(orow + dd)     = *(const float4*)(er + dd);
        *(float4*)(orow + dd + 4) = *(const float4*)(er + dd + 4);
    }

    float lsum = (q == 0) ? (zsq_g[row] + bsc * (1.0f / 1024.0f)) : 0.f;
    #pragma unroll
    for (int off = 32; off >= 1; off >>= 1) lsum += __shfl_down(lsum, off);
    if (lane == 0) s_red[wave] = lsum;
    __syncthreads();
    if (tid == 0)
        atomicAdd(loss_slot, (s_red[0] + s_red[1] + s_red[2] + s_red[3]) * loss_scale);
}

// ---- Fallback (round-2 structure, verified) — only if ws too small. --------
__global__ __launch_bounds__(256) void vq_prep_fb(const float* __restrict__ emb,
                                                  float* __restrict__ eTe,
                                                  float* __restrict__ loss_slot) {
    if (blockIdx.x == 0 && threadIdx.x == 0) *loss_slot = 0.0f;
    if (!eTe) return;
    int gtid = blockIdx.x * 256 + threadIdx.x;
    int code = gtid >> 6;
    int lane = threadIdx.x & 63;
    if (code >= K_CODES) return;
    float4 v = ((const float4*)(emb + (size_t)code * D_DIM))[lane];
    float s = v.x * v.x + v.y * v.y + v.z * v.z + v.w * v.w;
    #pragma unroll
    for (int off = 32; off >= 1; off >>= 1) s += __shfl_down(s, off);
    if (lane == 0) eTe[code] = s;
}

__global__ __launch_bounds__(128) void vq_main_fb(const float* __restrict__ z,
                                                  const float* __restrict__ emb,
                                                  const float* __restrict__ eTe_g,
                                                  float* __restrict__ out,
                                                  float* __restrict__ loss_slot,
                                                  float loss_scale) {
    __shared__ __align__(16) f16 sE[128 * D_DIM];
    __shared__ float s_ete[128];
    __shared__ int   s_idx2[128];
    __shared__ float s_red2[2];

    const int tid  = threadIdx.x;
    const int wave = tid >> 6;
    const int lane = tid & 63;
    const int m    = lane & 15;
    const int q    = lane >> 4;
    const size_t row0 = (size_t)blockIdx.x * 128 + (size_t)wave * 64;

    f16x8 A[4][8];
    #pragma unroll
    for (int st = 0; st < 4; st++) {
        const float* zr = z + (row0 + st * 16 + m) * D_DIM;
        #pragma unroll
        for (int s = 0; s < 8; s++) {
            const float* p = zr + s * 32 + q * 8;
            float4 v0 = *(const float4*)p;
            float4 v1 = *(const float4*)(p + 4);
            f16x8 a = {(f16)v0.x, (f16)v0.y, (f16)v0.z, (f16)v0.w,
                       (f16)v1.x, (f16)v1.y, (f16)v1.z, (f16)v1.w};
            A[st][s] = a;
        }
    }
    float best[4][4]; int bidx[4][4];
    #pragma unroll
    for (int st = 0; st < 4; st++)
        #pragma unroll
        for (int r = 0; r < 4; r++) { best[st][r] = __builtin_inff(); bidx[st][r] = 0; }

    const f16x8* sE8 = (const f16x8*)sE;
    #pragma unroll 1
    for (int sp = 0; sp < 8; sp++) {
        __syncthreads();
        if (eTe_g) s_ete[tid] = 1024.0f * eTe_g[sp * 128 + tid];
        else {
            const float* p = emb + (size_t)(sp * 128 + tid) * D_DIM;
            float ss = 0.f;
            for (int j = 0; j < D_DIM / 4; j++) {
                float4 v = ((const float4*)p)[j];
                ss += v.x * v.x + v.y * v.y + v.z * v.z + v.w * v.w;
            }
            s_ete[tid] = 1024.0f * ss;
        }
        const float* ebase = emb + (size_t)sp * 128 * D_DIM;
        #pragma unroll 4
        for (int it = 0; it < 32; it++) {
            int ch = it * 128 + tid;
            int cc = ((ch >> 9) << 4) | (ch & 15);
            int gg = (ch >> 4) & 31;
            const float* p = ebase + cc * D_DIM + gg * 8;
            float4 v0 = *(const float4*)p;
            float4 v1 = *(const float4*)(p + 4);
            f16x8 h = {(f16)(v0.x * 1024.f), (f16)(v0.y * 1024.f),
                       (f16)(v0.z * 1024.f), (f16)(v0.w * 1024.f),
                       (f16)(v1.x * 1024.f), (f16)(v1.y * 1024.f),
                       (f16)(v1.z * 1024.f), (f16)(v1.w * 1024.f)};
            *(f16x8*)(sE + (size_t)ch * 8) = h;
        }
        __syncthreads();
        for (int ct = 0; ct < 8; ct++) {
            f32x4 acc[4];
            #pragma unroll
            for (int st = 0; st < 4; st++) acc[st] = (f32x4){0.f, 0.f, 0.f, 0.f};
            #pragma unroll
            for (int s = 0; s < 8; s++) {
                f16x8 bh = sE8[ct * 512 + s * 64 + lane];
                #pragma unroll
                for (int st = 0; st < 4; st++)
                    acc[st] = __builtin_amdgcn_mfma_f32_16x16x32_f16(A[st][s], bh, acc[st], 0, 0, 0);
            }
            int codeL = ct * 16 + m;
            float ete = s_ete[codeL];
            int code  = sp * 128 + codeL;
            #pragma unroll
            for (int st = 0; st < 4; st++)
                #pragma unroll
                for (int r = 0; r < 4; r++) {
                    float sc = fmaf(-2.0f, acc[st][r], ete);
                    if (sc < best[st][r]) { best[st][r] = sc; bidx[st][r] = code; }
                }
        }
    }
    #pragma unroll
    for (int st = 0; st < 4; st++)
        #pragma unroll
        for (int r = 0; r < 4; r++) {
            float b = best[st][r]; int bi = bidx[st][r];
            #pragma unroll
            for (int off = 8; off >= 1; off >>= 1) {
                float ob = __shfl_xor(b, off);
                int   oi = __shfl_xor(bi, off);
                if (ob < b || (ob == b && oi < bi)) { b = ob; bi = oi; }
            }
            if (m == 0) s_idx2[wave * 64 + st * 16 + q * 4 + r] = bi;
        }
    __syncthreads();
    float lsum = 0.f;
    #pragma unroll
    for (int st = 0; st < 4; st++) {
        int rl = wave * 64 + st * 16 + m;
        int idxv = s_idx2[rl];
        const float* er = emb + (size_t)idxv * D_DIM;
        float* orow = out + ((size_t)blockIdx.x * 128 + rl) * D_DIM;
        #pragma unroll
        for (int s = 0; s < 8; s++) {
            int dd = s * 32 + q * 8;
            float4 e0 = *(const float4*)(er + dd);
            float4 e1 = *(const float4*)(er + dd + 4);
            *(float4*)(orow + dd)     = e0;
            *(float4*)(orow + dd + 4) = e1;
            f16x8 a = A[st][s];
            float d0 = e0.x - (float)a[0], d1 = e0.y - (float)a[1];
            float d2 = e0.z - (float)a[2], d3 = e0.w - (float)a[3];
            float d4 = e1.x - (float)a[4], d5 = e1.y - (float)a[5];
            float d6 = e1.z - (float)a[6], d7 = e1.w - (float)a[7];
            lsum += d0*d0 + d1*d1 + d2*d2 + d3*d3 + d4*d4 + d5*d5 + d6*d6 + d7*d7;
        }
    }
    #pragma unroll
    for (int off = 32; off >= 1; off >>= 1) lsum += __shfl_down(lsum, off);
    if (lane == 0) s_red2[wave] = lsum;
    __syncthreads();
    if (tid == 0) atomicAdd(loss_slot, (s_red2[0] + s_red2[1]) * loss_scale);
}

extern "C" void kernel_launch(void* const* d_in, const int* in_sizes, int n_in,
                              void* d_out, int out_size, void* d_ws, size_t ws_size,
                              hipStream_t stream) {
    const float* z   = (const float*)d_in[0];
    const float* emb = (const float*)d_in[1];
    float* out = (float*)d_out;
    float* loss_slot = out + (size_t)in_sizes[0];
    float loss_scale = 1.25f / (float)in_sizes[0];

    // ws layout: emb8 (256 KB) | eTe (4 KB) | pairs (2x32768 float2 = 512 KB)
    //          | zsq (128 KB)
    const size_t off_eTe   = (size_t)K_CODES * D_DIM;          // 262144
    const size_t off_pairs = off_eTe + K_CODES * sizeof(float);
    const size_t off_zsq   = off_pairs + 2ull * NROWS_TOT * sizeof(float2);
    const size_t need      = off_zsq + (size_t)NROWS_TOT * sizeof(float);

    if (ws_size >= need) {
        char*   emb8  = (char*)d_ws;
        float*  eTe   = (float*)((char*)d_ws + off_eTe);
        float2* pairs = (float2*)((char*)d_ws + off_pairs);
        float*  zsq   = (float*)((char*)d_ws + off_zsq);
        vq_prep<<<256, 256, 0, stream>>>(emb, emb8, eTe, loss_slot);
        vq_score<<<512, 256, 0, stream>>>(z, emb8, eTe, pairs, zsq);
        vq_final<<<512, 256, 0, stream>>>(emb, pairs, zsq, out, loss_slot, loss_scale);
    } else {
        float* eTe = (ws_size >= K_CODES * sizeof(float)) ? (float*)d_ws : nullptr;
        vq_prep_fb<<<K_CODES / 4, 256, 0, stream>>>(emb, eTe, loss_slot);
        vq_main_fb<<<NROWS_TOT / 128, 128, 0, stream>>>(z, emb, eTe, out, loss_slot, loss_scale);
    }
}